// Round 5
// baseline (106.978 us; speedup 1.0000x reference)
//
#include <hip/hip_runtime.h>

// Problem constants (GATLayer): B=4, N=2048, TOKEN_DIM=512, HIDDEN=128
// IO dtype: fp32. Internally: bf16 MFMA with fp32 accumulate.
// v11 (resubmit; round-4 run died to container-acquisition failure, not the
// kernel -- source re-audited: uniform barriers, LDS 52.9KB, in-bounds).
//   k_prep : fc_w fp32 -> bf16 (RTNE) once into workspace.
//   k_fused: v9 shape (256 blocks x 1024 thr; twin waves share Wb via L1).
//   k_attn : k-split consumers. Wave wv: d-group (wv&3)*32 (two 16-wide
//            d-tiles), k-half h=wv>>2 of each 256-j chunk. Each A-frag read
//            feeds 4 MFMAs (2 i-subtiles x 2 d-tiles) -> per-CU LDS reads
//            halve (128KB -> 64KB per chunk). Partial sums combined through
//            LDS at the end (h0 stores, h1 adds+scales+writes out).
//            Producer mapping + 16x16x32 MFMA layouts unchanged (validated).
#define NB      4
#define NTOK    2048
#define TOKDIM  512
#define HID     128
#define NROWS   (NB * NTOK)      // 8192
#define LN_EPS  1e-5f
#define NEG_SLOPE 0.01f

typedef short bf16x8 __attribute__((ext_vector_type(8)));   // 8 bf16 in 4 VGPRs
typedef float f32x4  __attribute__((ext_vector_type(4)));

static __device__ __forceinline__ unsigned short f2bf(float f) {
    union { float f; unsigned int i; } v; v.f = f;
    unsigned int i = v.i;
    i += 0x7FFFu + ((i >> 16) & 1u);   // round-to-nearest-even
    return (unsigned short)(i >> 16);
}

// ---------------------------------------------------------------------------
// k_prep: convert fc_w (128x512 fp32) -> bf16 once. 64 blocks x 256 thr.
// ---------------------------------------------------------------------------
__global__ __launch_bounds__(256) void k_prep(const float* __restrict__ W,
                                              unsigned short* __restrict__ Wb) {
    const int g = blockIdx.x * 256 + threadIdx.x;   // 0..16383
    float4 v = *(const float4*)(W + (size_t)g * 4);
    ushort4 o;
    o.x = f2bf(v.x); o.y = f2bf(v.y); o.z = f2bf(v.z); o.w = f2bf(v.w);
    *(ushort4*)(Wb + (size_t)g * 4) = o;
}

// ---------------------------------------------------------------------------
// k_fused (v9): per 32-row tile: FC (MFMA, A from LDS-staged bf16 X, B from
// pre-converted bf16 Wb) + bias + LayerNorm + scores + transposed hT write.
// Grid 256 blocks x 1024 thr (16 waves). Wave wv: n-cols [(wv&7)*16,+16),
// row-half (wv>>3)*16. Twin waves (wv, wv+8) read identical Wb slices (L1).
// ---------------------------------------------------------------------------
__global__ __launch_bounds__(1024) void k_fused(const float* __restrict__ X,
                                                const unsigned short* __restrict__ Wb,
                                                const float* __restrict__ fcb,
                                                const float* __restrict__ attnw,
                                                const float* __restrict__ attnb,
                                                const float* __restrict__ lng,
                                                const float* __restrict__ lnb,
                                                unsigned short* __restrict__ hT,
                                                float* __restrict__ srow,
                                                float* __restrict__ cc) {
    __shared__ char smem[33280 + 32 * 132 * 4];      // 50176 B
    unsigned short* ldsX = (unsigned short*)smem;    // [32][520]
    unsigned short* ldsT = (unsigned short*)smem;    // [128][36] (reuse)
    float* hfull = (float*)(smem + 33280);           // [32][132]

    const int tid   = threadIdx.x;
    const int wv    = tid >> 6;
    const int lane  = tid & 63;
    const int m     = lane & 15;
    const int q     = lane >> 4;
    const int rowbase = blockIdx.x * 32;
    const int nbase   = (wv & 7) * 16;
    const int rhalf   = (wv >> 3) * 16;              // 0 or 16

    // ---- phase A: stage X tile (32 rows) -> LDS bf16
    {
        const int r  = tid >> 5;            // 0..31
        const int c0 = (tid & 31) * 16;     // 0..496
        const float* xp = X + (size_t)(rowbase + r) * TOKDIM + c0;
        bf16x8 v0, v1;
#pragma unroll
        for (int u = 0; u < 8; ++u) v0[u] = (short)f2bf(xp[u]);
#pragma unroll
        for (int u = 0; u < 8; ++u) v1[u] = (short)f2bf(xp[8 + u]);
        *(bf16x8*)&ldsX[r * 520 + c0]     = v0;
        *(bf16x8*)&ldsX[r * 520 + c0 + 8] = v1;
    }
    __syncthreads();

    // ---- phase B: MFMA. A[m][k] from ldsX (row-half offset), B from bf16 Wb.
    const unsigned short* wp = Wb + (size_t)(nbase + m) * TOKDIM + q * 8;
    f32x4 acc = {0.f, 0.f, 0.f, 0.f};
#pragma unroll
    for (int kk = 0; kk < TOKDIM / 32; ++kk) {
        bf16x8 a = *(const bf16x8*)&ldsX[(rhalf + m) * 520 + kk * 32 + q * 8];
        bf16x8 b = *(const bf16x8*)(wp + kk * 32);
        acc = __builtin_amdgcn_mfma_f32_16x16x32_bf16(a, b, acc, 0, 0, 0);
    }

    // ---- phase C: acc (+fc_b) -> hfull LDS  (validated C/D mapping)
    {
        const float bias = fcb[nbase + m];
#pragma unroll
        for (int r = 0; r < 4; ++r)
            hfull[(rhalf + q * 4 + r) * 132 + nbase + m] = acc[r] + bias;
    }
    __syncthreads();   // hfull ready; ldsX dead (safe to reuse as ldsT)

    // ---- phase D: LN + scores; write bf16 h into ldsT transposed
    {
        const int r   = tid >> 5;           // row 0..31
        const int l32 = tid & 31;
        const int c0  = l32 * 4;
        float4 hv = *(const float4*)&hfull[r * 132 + c0];
        float v[4] = {hv.x, hv.y, hv.z, hv.w};

        float s  = v[0] + v[1] + v[2] + v[3];
        float ss = v[0]*v[0] + v[1]*v[1] + v[2]*v[2] + v[3]*v[3];
#pragma unroll
        for (int d = 1; d < 32; d <<= 1) {
            s  += __shfl_xor(s,  d, 64);
            ss += __shfl_xor(ss, d, 64);
        }
        float mu  = s * (1.f / HID);
        float var = ss * (1.f / HID) - mu * mu;
        float rs  = rsqrtf(var + LN_EPS);

        float n[4], sr = 0.f, sc = 0.f;
#pragma unroll
        for (int k = 0; k < 4; ++k) {
            n[k] = lng[c0 + k] * (v[k] - mu) * rs + lnb[c0 + k];
            sr += n[k] * attnw[c0 + k];
            sc += n[k] * attnw[HID + c0 + k];
            ldsT[(c0 + k) * 36 + r] = f2bf(n[k]);
        }
#pragma unroll
        for (int d = 1; d < 32; d <<= 1) {
            sr += __shfl_xor(sr, d, 64);
            sc += __shfl_xor(sc, d, 64);
        }
        if (l32 == 0) {
            int grow = rowbase + r;
            srow[grow] = sr;
            cc[grow]   = sc + attnb[0];
        }
    }
    __syncthreads();

    // ---- phase E: coalesced hT write. thread t: d = t>>3, 4 j's of 32.
    {
        const int d  = tid >> 3;                   // 0..127
        const int j4 = (tid & 7) * 4;              // 0..28
        const int b    = blockIdx.x >> 6;          // 64 blocks per batch
        const int jblk = (blockIdx.x & 63) * 32;
        ushort4 o;
        o.x = ldsT[d * 36 + j4 + 0];
        o.y = ldsT[d * 36 + j4 + 1];
        o.z = ldsT[d * 36 + j4 + 2];
        o.w = ldsT[d * 36 + j4 + 3];
        *(ushort4*)(hT + ((size_t)(b * HID + d)) * NTOK + jblk + j4) = o;
    }
}

// ---------------------------------------------------------------------------
// k_attn v9 (k-split): 256 blocks x 512 thr (8 waves); block owns 32 i-rows;
// j in 8 chunks of 256.
// Producer (all threads, unchanged): thread covers (i_loc=tid>>4,
// jseg=(tid&15)*16); produce(ch+1) overlaps consume(ch) across the barrier.
// Consumer: wave wv -> d-group (wv&3)*32 (d-tiles at +0 and +16), k-half
// h=wv>>2 (j-offset h*128 within each chunk, 4 s-steps of 32). Per s-step:
// 2 ds_reads (a0 rows m, a1 rows 16+m) feed 4 MFMAs. Partial accs combined
// through pC at the end: h0 waves store, h1 waves add + scale + write out.
// ---------------------------------------------------------------------------
static __device__ __forceinline__ void produce_chunk(
        unsigned short* __restrict__ dst,   // &pP[buf][i_loc][jseg]
        float ci, float4 s0, float4 s1, float4 s2, float4 s3,
        float& lsum) {
    float sv[16] = {s0.x, s0.y, s0.z, s0.w, s1.x, s1.y, s1.z, s1.w,
                    s2.x, s2.y, s2.z, s2.w, s3.x, s3.y, s3.z, s3.w};
    bf16x8 v0, v1;
#pragma unroll
    for (int u = 0; u < 8; ++u) {
        float z = ci + sv[u];
        z = fmaxf(z, NEG_SLOPE * z);
        float p = __expf(z);
        lsum += p;
        v0[u] = (short)f2bf(p);
    }
#pragma unroll
    for (int u = 0; u < 8; ++u) {
        float z = ci + sv[8 + u];
        z = fmaxf(z, NEG_SLOPE * z);
        float p = __expf(z);
        lsum += p;
        v1[u] = (short)f2bf(p);
    }
    *(bf16x8*)dst       = v0;
    *(bf16x8*)(dst + 8) = v1;
}

__global__ __launch_bounds__(512) void k_attn(const unsigned short* __restrict__ hT,
                                              const float* __restrict__ srow,
                                              const float* __restrict__ cc,
                                              float* __restrict__ out) {
    __shared__ unsigned short pP[2][32][264];   // 2 x 16896 B, +8 pad
    __shared__ float pC[32][132];               // partial acc combine, 16896 B
    __shared__ float pDen[32][16];              // 2 KB
    __shared__ float denv[32];

    const int tid  = threadIdx.x;
    const int wv   = tid >> 6;
    const int lane = tid & 63;
    const int m    = lane & 15;
    const int q    = lane >> 4;
    const int rowbase = blockIdx.x * 32;     // global row base
    const int b    = blockIdx.x >> 6;        // 64 blocks per batch

    // consumer k-split mapping
    const int dgrp = (wv & 3) * 32;          // d-group base (0/32/64/96)
    const int h    = wv >> 2;                // k-half 0/1
    const int hk   = h * 128;                // j offset within chunk

    // producer indices (unchanged, validated)
    const int i_loc = tid >> 4;              // 0..31
    const int jseg  = (tid & 15) * 16;       // 0..240
    const float ci  = cc[rowbase + i_loc];
    const float* sp = srow + (size_t)b * NTOK + jseg;

    // consumer B pointers: d-rows dgrp+m and dgrp+16+m, k-half offset
    const unsigned short* hp0 =
        hT + ((size_t)(b * HID + dgrp + m)) * NTOK + hk + q * 8;
    const unsigned short* hp1 = hp0 + 16 * NTOK;

    // 4 partial accumulators: [i-subtile][d-tile]
    f32x4 acc00 = {0.f, 0.f, 0.f, 0.f};
    f32x4 acc01 = {0.f, 0.f, 0.f, 0.f};
    f32x4 acc10 = {0.f, 0.f, 0.f, 0.f};
    f32x4 acc11 = {0.f, 0.f, 0.f, 0.f};
    float lsum = 0.f;

    // ---- prologue: srow(0)+B(0) loads; produce chunk 0; load srow(1)
    float4 s0 = *(const float4*)(sp);
    float4 s1 = *(const float4*)(sp + 4);
    float4 s2 = *(const float4*)(sp + 8);
    float4 s3 = *(const float4*)(sp + 12);
    bf16x8 bc0[4], bc1[4], bn0[4], bn1[4];
#pragma unroll
    for (int s = 0; s < 4; ++s) {
        bc0[s] = *(const bf16x8*)(hp0 + s * 32);
        bc1[s] = *(const bf16x8*)(hp1 + s * 32);
    }

    produce_chunk(&pP[0][i_loc][jseg], ci, s0, s1, s2, s3, lsum);

    float4 n0, n1, n2, n3;
    {
        const float* spn = sp + 256;
        n0 = *(const float4*)(spn);
        n1 = *(const float4*)(spn + 4);
        n2 = *(const float4*)(spn + 8);
        n3 = *(const float4*)(spn + 12);
    }

    __syncthreads();   // pP[0] ready

#pragma unroll
    for (int ch = 0; ch < 8; ++ch) {
        if (ch < 7) {
            // ---- produce chunk ch+1 (other buffer; read only after barrier)
            produce_chunk(&pP[(ch + 1) & 1][i_loc][jseg], ci, n0, n1, n2, n3, lsum);

            // ---- load srow(ch+2)
            if (ch < 6) {
                const float* spn = sp + (ch + 2) * 256;
                n0 = *(const float4*)(spn);
                n1 = *(const float4*)(spn + 4);
                n2 = *(const float4*)(spn + 8);
                n3 = *(const float4*)(spn + 12);
            }
            // ---- prefetch B(ch+1)
            const unsigned short* g0 = hp0 + (ch + 1) * 256;
            const unsigned short* g1 = hp1 + (ch + 1) * 256;
#pragma unroll
            for (int s = 0; s < 4; ++s) {
                bn0[s] = *(const bf16x8*)(g0 + s * 32);
                bn1[s] = *(const bf16x8*)(g1 + s * 32);
            }
        }

        // ---- consume chunk ch: 4 s-steps; each A-read feeds 4 MFMAs
#pragma unroll
        for (int s = 0; s < 4; ++s) {
            bf16x8 a0 = *(const bf16x8*)&pP[ch & 1][m][hk + s * 32 + q * 8];
            bf16x8 a1 = *(const bf16x8*)&pP[ch & 1][16 + m][hk + s * 32 + q * 8];
            acc00 = __builtin_amdgcn_mfma_f32_16x16x32_bf16(a0, bc0[s], acc00, 0, 0, 0);
            acc01 = __builtin_amdgcn_mfma_f32_16x16x32_bf16(a0, bc1[s], acc01, 0, 0, 0);
            acc10 = __builtin_amdgcn_mfma_f32_16x16x32_bf16(a1, bc0[s], acc10, 0, 0, 0);
            acc11 = __builtin_amdgcn_mfma_f32_16x16x32_bf16(a1, bc1[s], acc11, 0, 0, 0);
        }

        __syncthreads();   // pP[(ch+1)&1] complete; chunk ch fully consumed

        if (ch < 7) {
#pragma unroll
            for (int s = 0; s < 4; ++s) { bc0[s] = bn0[s]; bc1[s] = bn1[s]; }
        }
    }

    // ---- denominators (producer mapping, unchanged)
    pDen[i_loc][tid & 15] = lsum;
    __syncthreads();
    if (tid < 32) {
        float d = 0.f;
#pragma unroll
        for (int k = 0; k < 16; ++k) d += pDen[tid][k];
        denv[tid] = 1.f / d;
    }
    // ---- h0 waves store partial accs to pC (row = i, col = d; pad 132)
    if (h == 0) {
#pragma unroll
        for (int r = 0; r < 4; ++r) {
            pC[q * 4 + r][dgrp + m]           = acc00[r];
            pC[q * 4 + r][dgrp + 16 + m]      = acc01[r];
            pC[16 + q * 4 + r][dgrp + m]      = acc10[r];
            pC[16 + q * 4 + r][dgrp + 16 + m] = acc11[r];
        }
    }
    __syncthreads();
    // ---- h1 waves: combine + scale + write out
    if (h == 1) {
#pragma unroll
        for (int r = 0; r < 4; ++r) {
            int r0 = q * 4 + r;
            float v00 = (pC[r0][dgrp + m]           + acc00[r]) * denv[r0];
            float v01 = (pC[r0][dgrp + 16 + m]      + acc01[r]) * denv[r0];
            float v10 = (pC[16 + r0][dgrp + m]      + acc10[r]) * denv[16 + r0];
            float v11 = (pC[16 + r0][dgrp + 16 + m] + acc11[r]) * denv[16 + r0];
            out[(size_t)(rowbase + r0) * HID + dgrp + m]           = v00;
            out[(size_t)(rowbase + r0) * HID + dgrp + 16 + m]      = v01;
            out[(size_t)(rowbase + 16 + r0) * HID + dgrp + m]      = v10;
            out[(size_t)(rowbase + 16 + r0) * HID + dgrp + 16 + m] = v11;
        }
    }
}

// ---------------------------------------------------------------------------
extern "C" void kernel_launch(void* const* d_in, const int* in_sizes, int n_in,
                              void* d_out, int out_size, void* d_ws, size_t ws_size,
                              hipStream_t stream) {
    const float* X     = (const float*)d_in[0]; // token_embedding [4,2048,512]
    const float* W     = (const float*)d_in[1]; // fc_w [128,512]
    const float* fcb   = (const float*)d_in[2]; // fc_b [128]
    const float* attnw = (const float*)d_in[3]; // attn_w [1,256]
    const float* attnb = (const float*)d_in[4]; // attn_b [1]
    const float* lng   = (const float*)d_in[5]; // ln_g [128]
    const float* lnb   = (const float*)d_in[6]; // ln_b [128]
    float* out = (float*)d_out;                 // h_prime [4,2048,128] fp32

    char* ws = (char*)d_ws;
    unsigned short* hT   = (unsigned short*)ws;                          // 2 MB
    float*          srow = (float*)(ws + 2u * 1024 * 1024);              // 32 KB
    float*          cchd = (float*)(ws + 2u * 1024 * 1024 + 32u * 1024); // 32 KB
    unsigned short* Wb   = (unsigned short*)(ws + 2u * 1024 * 1024 + 64u * 1024); // 128 KB

    k_prep <<<64, 256, 0, stream>>>(W, Wb);
    k_fused<<<NROWS / 32, 1024, 0, stream>>>(X, Wb, fcb, attnw, attnb, lng, lnb,
                                             hT, srow, cchd);
    k_attn <<<NROWS / 32, 512, 0, stream>>>(hT, srow, cchd, out);
}